// Round 11
// baseline (1225.677 us; speedup 1.0000x reference)
//
#include <hip/hip_runtime.h>
#include <hip/hip_cooperative_groups.h>
#include <math.h>

namespace cg = cooperative_groups;

#define N_NODES 100000
#define EMB 64
#define N_EDGES 1200000
#define N_ELEM (N_NODES * EMB)     // 6,400,000
#define GRID 1024
#define TPB 256
#define NTHREADS (GRID * TPB)      // 262,144
#define NWAVES (NTHREADS / 64)     // 4,096
#define SCAN_CHUNKS ((N_NODES + TPB - 1) / TPB)   // 391  (fused path)
#define SCAN_CHUNK2 1024                           // split-path scan chunk
#define SCAN_NBLK2 ((N_NODES + SCAN_CHUNK2 - 1) / SCAN_CHUNK2)   // 98

// ---------------------------------------------------------------------------
// Threefry-2x32, 20 rounds — JAX partitionable mode (verified R6/R7/R9)
// ---------------------------------------------------------------------------
__device__ __forceinline__ unsigned rotl32(unsigned v, int r) {
    return (v << r) | (v >> (32 - r));
}

__device__ __forceinline__ void threefry2x32(unsigned k0, unsigned k1,
                                             unsigned c0, unsigned c1,
                                             unsigned& o0, unsigned& o1) {
    const unsigned ks0 = k0;
    const unsigned ks1 = k1;
    const unsigned ks2 = k0 ^ k1 ^ 0x1BD11BDAu;
    unsigned x0 = c0 + ks0;
    unsigned x1 = c1 + ks1;
#define TF_RND(r) { x0 += x1; x1 = rotl32(x1, r); x1 ^= x0; }
    TF_RND(13) TF_RND(15) TF_RND(26) TF_RND(6)
    x0 += ks1; x1 += ks2 + 1u;
    TF_RND(17) TF_RND(29) TF_RND(16) TF_RND(24)
    x0 += ks2; x1 += ks0 + 2u;
    TF_RND(13) TF_RND(15) TF_RND(26) TF_RND(6)
    x0 += ks0; x1 += ks1 + 3u;
    TF_RND(17) TF_RND(29) TF_RND(16) TF_RND(24)
    x0 += ks1; x1 += ks2 + 4u;
    TF_RND(13) TF_RND(15) TF_RND(26) TF_RND(6)
    x0 += ks2; x1 += ks0 + 5u;
#undef TF_RND
    o0 = x0;
    o1 = x1;
}

__device__ __forceinline__ bool drop_keep(unsigned i) {
    unsigned o0, o1;
    threefry2x32(0u, 42u, 0u, i, o0, o1);
    unsigned bits = o0 ^ o1;
    float u = __uint_as_float((bits >> 9) | 0x3f800000u) - 1.0f;
    return u < 0.9f;
}

// ---------------------------------------------------------------------------
// Aggregation body (shared by fused + split paths): one wave64 per node
// (stride = nwaves); 4 groups of 16 lanes; lane = float4 of dims; x2 unroll.
// MODE 0: y = sum; acc = x(own) + sum
// MODE 1: y = sum; acc += sum
// MODE 2: acc = dropout((acc + sum)/4)   [no y write]
// ---------------------------------------------------------------------------
template <int MODE>
__device__ __forceinline__ void agg_body(const int* __restrict__ rowptr,
                                         const int2* __restrict__ edges,
                                         const float* __restrict__ x,
                                         float* __restrict__ y,
                                         float* __restrict__ acc,
                                         int gwid, int nwaves, int lane) {
    const int g = lane >> 4;       // group 0..3
    const int l16 = lane & 15;     // dims 4*l16 .. 4*l16+3
    const float* xb = x + (l16 << 2);
    for (int wv = gwid; wv < N_NODES; wv += nwaves) {
        const int begin = rowptr[wv];
        const int end = rowptr[wv + 1];
        float4 s = make_float4(0.f, 0.f, 0.f, 0.f);
        int j = begin + g;
        for (; j + 4 < end; j += 8) {       // pair (j, j+4): 8 gathers in flight/wave
            int2 r0 = edges[j];
            int2 r1 = edges[j + 4];
            float n0 = __int_as_float(r0.y);
            float n1 = __int_as_float(r1.y);
            const float4 v0 = *reinterpret_cast<const float4*>(xb + (size_t)r0.x * EMB);
            const float4 v1 = *reinterpret_cast<const float4*>(xb + (size_t)r1.x * EMB);
            s.x += v0.x * n0 + v1.x * n1;
            s.y += v0.y * n0 + v1.y * n1;
            s.z += v0.z * n0 + v1.z * n1;
            s.w += v0.w * n0 + v1.w * n1;
        }
        if (j < end) {
            int2 r0 = edges[j];
            float n0 = __int_as_float(r0.y);
            const float4 v0 = *reinterpret_cast<const float4*>(xb + (size_t)r0.x * EMB);
            s.x += v0.x * n0; s.y += v0.y * n0; s.z += v0.z * n0; s.w += v0.w * n0;
        }
        // reduce across the 4 groups (lane bits 4,5)
        s.x += __shfl_xor(s.x, 16, 64); s.y += __shfl_xor(s.y, 16, 64);
        s.z += __shfl_xor(s.z, 16, 64); s.w += __shfl_xor(s.w, 16, 64);
        s.x += __shfl_xor(s.x, 32, 64); s.y += __shfl_xor(s.y, 32, 64);
        s.z += __shfl_xor(s.z, 32, 64); s.w += __shfl_xor(s.w, 32, 64);

        const size_t ridx = (size_t)wv * EMB + (l16 << 2);
        if (MODE == 0) {
            if (g == 0) *reinterpret_cast<float4*>(y + ridx) = s;
            if (g == 1) {
                float4 own = *reinterpret_cast<const float4*>(x + ridx);
                *reinterpret_cast<float4*>(acc + ridx) =
                    make_float4(own.x + s.x, own.y + s.y, own.z + s.z, own.w + s.w);
            }
        } else if (MODE == 1) {
            if (g == 0) *reinterpret_cast<float4*>(y + ridx) = s;
            if (g == 1) {
                float4 a = *reinterpret_cast<const float4*>(acc + ridx);
                *reinterpret_cast<float4*>(acc + ridx) =
                    make_float4(a.x + s.x, a.y + s.y, a.z + s.z, a.w + s.w);
            }
        } else {
            unsigned rowbase = (unsigned)((size_t)wv * EMB);
            bool k = drop_keep(rowbase + (unsigned)((l16 << 2) + g));
            unsigned long long mask = __ballot(k);
            if (g == 0) {
                float4 a = *reinterpret_cast<const float4*>(acc + ridx);
                float4 t = make_float4(a.x + s.x, a.y + s.y, a.z + s.z, a.w + s.w);
                const float sc = 0.25f / 0.9f;
                float4 o;
                o.x = ((mask >> (0 * 16 + l16)) & 1ull) ? t.x * sc : 0.f;
                o.y = ((mask >> (1 * 16 + l16)) & 1ull) ? t.y * sc : 0.f;
                o.z = ((mask >> (2 * 16 + l16)) & 1ull) ? t.z * sc : 0.f;
                o.w = ((mask >> (3 * 16 + l16)) & 1ull) ? t.w * sc : 0.f;
                *reinterpret_cast<float4*>(acc + ridx) = o;
            }
        }
    }
}

// ---------------------------------------------------------------------------
// FUSED cooperative kernel: hist -> scan -> scatter -> 3x agg
// ---------------------------------------------------------------------------
__global__ __launch_bounds__(TPB, 4)
void kfused(const float* __restrict__ emb, const int* __restrict__ src,
            const int* __restrict__ dst,
            int* __restrict__ cnt, int* __restrict__ cursor,
            int* __restrict__ bsum, int* __restrict__ bofs,
            int* __restrict__ rowptr, float* __restrict__ dis,
            int2* __restrict__ edges,
            float* __restrict__ bufA, float* __restrict__ bufB,
            float* __restrict__ acc) {
    cg::grid_group grid = cg::this_grid();
    const int tid = threadIdx.x;
    const int bid = blockIdx.x;
    const int gtid = bid * TPB + tid;
    const int lane = tid & 63;
    const int wid = tid >> 6;
    const int gwid = gtid >> 6;

    // P0: zero cnt
    for (int i = gtid; i < N_NODES; i += NTHREADS) cnt[i] = 0;
    grid.sync();

    // P1: degree histogram
    for (int e = gtid; e < N_EDGES; e += NTHREADS) atomicAdd(&cnt[dst[e]], 1);
    grid.sync();

    // P2a: per-256-chunk local exclusive scan (into cursor) + chunk totals + dis
    {
        __shared__ int wsum[4];
        for (int c = bid; c < SCAN_CHUNKS; c += GRID) {
            int i = c * TPB + tid;
            int v = (i < N_NODES) ? cnt[i] : 0;
            if (i < N_NODES) dis[i] = (v > 0) ? rsqrtf((float)v) : 0.0f;
            int x = v;
#pragma unroll
            for (int off = 1; off < 64; off <<= 1) {
                int t = __shfl_up(x, off, 64);
                if (lane >= off) x += t;
            }
            if (lane == 63) wsum[wid] = x;
            __syncthreads();
            int w0 = wsum[0], w1 = wsum[1], w2 = wsum[2], w3 = wsum[3];
            int wexc = (wid > 0 ? w0 : 0) + (wid > 1 ? w1 : 0) + (wid > 2 ? w2 : 0);
            if (i < N_NODES) cursor[i] = (x + wexc) - v;
            if (tid == 0) bsum[c] = w0 + w1 + w2 + w3;
            __syncthreads();
        }
    }
    grid.sync();

    // P2b: exclusive scan of the 391 chunk totals (one wave of block 0)
    if (bid == 0 && wid == 0) {
        int carry = 0;
        for (int base = 0; base < SCAN_CHUNKS; base += 64) {
            int idx = base + lane;
            int v = (idx < SCAN_CHUNKS) ? bsum[idx] : 0;
            int x = v;
#pragma unroll
            for (int off = 1; off < 64; off <<= 1) {
                int t = __shfl_up(x, off, 64);
                if (lane >= off) x += t;
            }
            if (idx < SCAN_CHUNKS) bofs[idx] = carry + x - v;
            carry += __shfl(x, 63, 64);
        }
    }
    grid.sync();

    // P2c: finalize rowptr & cursor
    for (int i = gtid; i < N_NODES; i += NTHREADS) {
        int r = cursor[i] + bofs[i >> 8];
        rowptr[i] = r;
        cursor[i] = r;
    }
    if (gtid == 0) rowptr[N_NODES] = N_EDGES;
    grid.sync();

    // P3: scatter edges dst-sorted, packed int2{src, norm}
    for (int e = gtid; e < N_EDGES; e += NTHREADS) {
        int s = src[e];
        int d = dst[e];
        int pos = atomicAdd(&cursor[d], 1);
        edges[pos] = make_int2(s, __float_as_int(dis[s] * dis[d]));
    }
    grid.sync();

    // P4-P6: 3 propagation layers; acc and final dropout fused
    agg_body<0>(rowptr, edges, emb, bufA, acc, gwid, NWAVES, lane);
    grid.sync();
    agg_body<1>(rowptr, edges, bufA, bufB, acc, gwid, NWAVES, lane);
    grid.sync();
    agg_body<2>(rowptr, edges, bufB, nullptr, acc, gwid, NWAVES, lane);
}

// ---------------------------------------------------------------------------
// SPLIT-path kernels (verified R9 fallback)
// ---------------------------------------------------------------------------
__global__ void k_zero(int* __restrict__ p, int n) {
    int i = blockIdx.x * blockDim.x + threadIdx.x;
    if (i < n) p[i] = 0;
}

__global__ void k_hist(const int* __restrict__ dst, int* __restrict__ cnt) {
    int e = blockIdx.x * blockDim.x + threadIdx.x;
    if (e < N_EDGES) atomicAdd(&cnt[dst[e]], 1);
}

__global__ void k_scan1(const int* __restrict__ cnt, int* __restrict__ local,
                        int* __restrict__ bsum, float* __restrict__ dis) {
    __shared__ int wsum[16];
    const int tid = threadIdx.x;
    const int lane = tid & 63;
    const int wid = tid >> 6;
    int i = blockIdx.x * SCAN_CHUNK2 + tid;
    int v = (i < N_NODES) ? cnt[i] : 0;
    if (i < N_NODES) dis[i] = (v > 0) ? rsqrtf((float)v) : 0.0f;
    int x = v;
#pragma unroll
    for (int off = 1; off < 64; off <<= 1) {
        int t = __shfl_up(x, off, 64);
        if (lane >= off) x += t;
    }
    if (lane == 63) wsum[wid] = x;
    __syncthreads();
    if (wid == 0 && lane < 16) {
        int w = wsum[lane];
#pragma unroll
        for (int off = 1; off < 16; off <<= 1) {
            int t = __shfl_up(w, off, 64);
            if (lane >= off) w += t;
        }
        wsum[lane] = w;
    }
    __syncthreads();
    int wexc = (wid == 0) ? 0 : wsum[wid - 1];
    if (i < N_NODES) local[i] = (x + wexc) - v;
    if (tid == 0) bsum[blockIdx.x] = wsum[15];
}

__global__ void k_scan2(const int* __restrict__ bsum, int* __restrict__ bofs) {
    __shared__ int sh[128];
    int t = threadIdx.x;
    int v = (t < SCAN_NBLK2) ? bsum[t] : 0;
    sh[t] = v;
    __syncthreads();
    for (int off = 1; off < 128; off <<= 1) {
        int add = (t >= off) ? sh[t - off] : 0;
        __syncthreads();
        sh[t] += add;
        __syncthreads();
    }
    if (t < SCAN_NBLK2) bofs[t] = sh[t] - v;
}

__global__ void k_scan3(int* __restrict__ cursor_local, const int* __restrict__ bofs,
                        int* __restrict__ rowptr) {
    int i = blockIdx.x * SCAN_CHUNK2 + threadIdx.x;
    if (i < N_NODES) {
        int r = cursor_local[i] + bofs[blockIdx.x];
        rowptr[i] = r;
        cursor_local[i] = r;
    }
    if (i == 0) rowptr[N_NODES] = N_EDGES;
}

__global__ void k_scatter(const int* __restrict__ src, const int* __restrict__ dst,
                          const float* __restrict__ dis, int* __restrict__ cursor,
                          int2* __restrict__ edges) {
    int e = blockIdx.x * blockDim.x + threadIdx.x;
    if (e >= N_EDGES) return;
    int s = src[e];
    int d = dst[e];
    int pos = atomicAdd(&cursor[d], 1);
    edges[pos] = make_int2(s, __float_as_int(dis[s] * dis[d]));
}

template <int MODE>
__global__ void k_agg(const int* __restrict__ rowptr, const int2* __restrict__ edges,
                      const float* __restrict__ x, float* __restrict__ y,
                      float* __restrict__ acc) {
    int gwid = (blockIdx.x * blockDim.x + threadIdx.x) >> 6;
    int lane = threadIdx.x & 63;
    if (gwid >= N_NODES) return;
    // nwaves = N_NODES stride makes the loop execute exactly once per wave
    agg_body<MODE>(rowptr, edges, x, y, acc, gwid, N_NODES, lane);
}

// ---------------------------------------------------------------------------
// Launch: try fused cooperative; fall back to split kernels on failure.
// ---------------------------------------------------------------------------
extern "C" void kernel_launch(void* const* d_in, const int* in_sizes, int n_in,
                              void* d_out, int out_size, void* d_ws, size_t ws_size,
                              hipStream_t stream) {
    const float* emb = (const float*)d_in[0];
    const int* eidx = (const int*)d_in[1];
    const int* src = eidx;             // edge_index[0]
    const int* dst = eidx + N_EDGES;   // edge_index[1]
    float* acc = (float*)d_out;

    // workspace layout (bytes; bufA/bufB 16B-aligned)
    char* ws = (char*)d_ws;
    int*   cnt     = (int*)(ws + 0);           // 100,000 ints
    int*   cursor  = (int*)(ws + 400000);      // 100,000 ints
    int*   bsum    = (int*)(ws + 800000);      // 391 max
    int*   bofs    = (int*)(ws + 801564);      // 391 max
    int*   rowptr  = (int*)(ws + 803128);      // 100,001
    float* dis     = (float*)(ws + 1203132);   // 100,000
    int2*  edges   = (int2*)(ws + 1603136);    // 1,200,000 int2 (8B-aligned)
    float* bufA    = (float*)(ws + 11203136);  // 6,400,000 (16B-aligned)
    float* bufB    = (float*)(ws + 36803136);  // 6,400,000; end ~62.4 MB

    const float* emb_a = emb;
    const int* src_a = src;
    const int* dst_a = dst;
    void* args[] = {
        (void*)&emb_a, (void*)&src_a, (void*)&dst_a,
        (void*)&cnt, (void*)&cursor, (void*)&bsum, (void*)&bofs,
        (void*)&rowptr, (void*)&dis, (void*)&edges,
        (void*)&bufA, (void*)&bufB, (void*)&acc
    };
    hipError_t err = hipLaunchCooperativeKernel((void*)kfused, dim3(GRID), dim3(TPB),
                                                args, 0, stream);
    if (err == hipSuccess) return;

    // ---- fallback: verified R9 split path ----
    const int BLK = 256;
    const int gE   = (N_EDGES + BLK - 1) / BLK;
    const int gN   = (N_NODES + BLK - 1) / BLK;
    const int gAgg = (N_NODES * 64 + BLK - 1) / BLK;

    k_zero<<<gN, BLK, 0, stream>>>(cnt, N_NODES);
    k_hist<<<gE, BLK, 0, stream>>>(dst, cnt);
    k_scan1<<<SCAN_NBLK2, SCAN_CHUNK2, 0, stream>>>(cnt, cursor, bsum, dis);
    k_scan2<<<1, 128, 0, stream>>>(bsum, bofs);
    k_scan3<<<SCAN_NBLK2, SCAN_CHUNK2, 0, stream>>>(cursor, bofs, rowptr);
    k_scatter<<<gE, BLK, 0, stream>>>(src, dst, dis, cursor, edges);
    k_agg<0><<<gAgg, BLK, 0, stream>>>(rowptr, edges, emb,  bufA, acc);
    k_agg<1><<<gAgg, BLK, 0, stream>>>(rowptr, edges, bufA, bufB, acc);
    k_agg<2><<<gAgg, BLK, 0, stream>>>(rowptr, edges, bufB, nullptr, acc);
}

// Round 12
// 368.382 us; speedup vs baseline: 3.3272x; 3.3272x over previous
//
#include <hip/hip_runtime.h>
#include <math.h>

#define N_NODES 100000
#define EMB 64
#define N_EDGES 1200000
#define N_ELEM (N_NODES * EMB)   // 6,400,000
#define SCAN_CHUNK 1024
#define SCAN_NBLK ((N_NODES + SCAN_CHUNK - 1) / SCAN_CHUNK)   // 98
#define NPART 8
#define PART_SIZE (N_NODES / NPART)    // 12,500 exact
#define SC_GRID 1024
#define SC_TPB 256

// ---------------------------------------------------------------------------
// Threefry-2x32, 20 rounds — JAX partitionable mode (verified R6/R7/R9/R11)
// ---------------------------------------------------------------------------
__device__ __forceinline__ unsigned rotl32(unsigned v, int r) {
    return (v << r) | (v >> (32 - r));
}

__device__ __forceinline__ void threefry2x32(unsigned k0, unsigned k1,
                                             unsigned c0, unsigned c1,
                                             unsigned& o0, unsigned& o1) {
    const unsigned ks0 = k0;
    const unsigned ks1 = k1;
    const unsigned ks2 = k0 ^ k1 ^ 0x1BD11BDAu;
    unsigned x0 = c0 + ks0;
    unsigned x1 = c1 + ks1;
#define TF_RND(r) { x0 += x1; x1 = rotl32(x1, r); x1 ^= x0; }
    TF_RND(13) TF_RND(15) TF_RND(26) TF_RND(6)
    x0 += ks1; x1 += ks2 + 1u;
    TF_RND(17) TF_RND(29) TF_RND(16) TF_RND(24)
    x0 += ks2; x1 += ks0 + 2u;
    TF_RND(13) TF_RND(15) TF_RND(26) TF_RND(6)
    x0 += ks0; x1 += ks1 + 3u;
    TF_RND(17) TF_RND(29) TF_RND(16) TF_RND(24)
    x0 += ks1; x1 += ks2 + 4u;
    TF_RND(13) TF_RND(15) TF_RND(26) TF_RND(6)
    x0 += ks2; x1 += ks0 + 5u;
#undef TF_RND
    o0 = x0;
    o1 = x1;
}

__device__ __forceinline__ bool drop_keep(unsigned i) {
    unsigned o0, o1;
    threefry2x32(0u, 42u, 0u, i, o0, o1);
    unsigned bits = o0 ^ o1;
    float u = __uint_as_float((bits >> 9) | 0x3f800000u) - 1.0f;
    return u < 0.9f;
}

// ---------------------------------------------------------------------------
// CSR construction (hist + 3-pass scan verified R9)
// ---------------------------------------------------------------------------
__global__ void k_hist(const int* __restrict__ dst, int* __restrict__ cnt) {
    int e = blockIdx.x * blockDim.x + threadIdx.x;
    if (e < N_EDGES) atomicAdd(&cnt[dst[e]], 1);
}

__global__ void k_scan1(const int* __restrict__ cnt, int* __restrict__ local,
                        int* __restrict__ bsum, float* __restrict__ dis) {
    __shared__ int wsum[16];
    const int tid = threadIdx.x;
    const int lane = tid & 63;
    const int wid = tid >> 6;
    int i = blockIdx.x * SCAN_CHUNK + tid;
    int v = (i < N_NODES) ? cnt[i] : 0;
    if (i < N_NODES) dis[i] = (v > 0) ? rsqrtf((float)v) : 0.0f;
    int x = v;
#pragma unroll
    for (int off = 1; off < 64; off <<= 1) {
        int t = __shfl_up(x, off, 64);
        if (lane >= off) x += t;
    }
    if (lane == 63) wsum[wid] = x;
    __syncthreads();
    if (wid == 0 && lane < 16) {
        int w = wsum[lane];
#pragma unroll
        for (int off = 1; off < 16; off <<= 1) {
            int t = __shfl_up(w, off, 64);
            if (lane >= off) w += t;
        }
        wsum[lane] = w;
    }
    __syncthreads();
    int wexc = (wid == 0) ? 0 : wsum[wid - 1];
    if (i < N_NODES) local[i] = (x + wexc) - v;
    if (tid == 0) bsum[blockIdx.x] = wsum[15];
}

__global__ void k_scan2(const int* __restrict__ bsum, int* __restrict__ bofs) {
    __shared__ int sh[128];
    int t = threadIdx.x;
    int v = (t < SCAN_NBLK) ? bsum[t] : 0;
    sh[t] = v;
    __syncthreads();
    for (int off = 1; off < 128; off <<= 1) {
        int add = (t >= off) ? sh[t - off] : 0;
        __syncthreads();
        sh[t] += add;
        __syncthreads();
    }
    if (t < SCAN_NBLK) bofs[t] = sh[t] - v;
}

__global__ void k_scan3(int* __restrict__ cursor_local, const int* __restrict__ bofs,
                        int* __restrict__ rowptr) {
    int i = blockIdx.x * SCAN_CHUNK + threadIdx.x;
    if (i < N_NODES) {
        int r = cursor_local[i] + bofs[blockIdx.x];
        rowptr[i] = r;
        cursor_local[i] = r;
    }
    if (i == 0) rowptr[N_NODES] = N_EDGES;
}

// dst-range partitioned scatter: block handles partition (bid & 7); all blocks
// of a partition grid-stride the full edge list and process only edges whose
// dst falls in their range. Writes to edges[] cluster per partition ->
// 64B-line merging instead of 1 line per 8B record.
__global__ void k_scatter(const int* __restrict__ src, const int* __restrict__ dst,
                          const float* __restrict__ dis, int* __restrict__ cursor,
                          int2* __restrict__ edges) {
    const int p = blockIdx.x & (NPART - 1);
    const int lo = p * PART_SIZE;
    const int hi = lo + PART_SIZE;
    const int stride = (SC_GRID / NPART) * SC_TPB;
    int e = (blockIdx.x >> 3) * SC_TPB + threadIdx.x;
    for (; e < N_EDGES; e += stride) {
        int d = dst[e];
        if (d >= lo && d < hi) {
            int s = src[e];
            int pos = atomicAdd(&cursor[d], 1);
            edges[pos] = make_int2(s, __float_as_int(dis[s] * dis[d]));
        }
    }
}

// ---------------------------------------------------------------------------
// Propagation v3: 4 nodes per wave, one per 16-lane group (16 lanes x float4
// = full 64-dim row). x4 edge unroll -> 16 row-gathers in flight per wave.
// No cross-lane reduction needed.
// MODE 0: y = sum; acc = x(own) + sum
// MODE 1: y = sum; acc += sum
// MODE 2: acc = dropout((acc + sum)/4)   [no y write]
// ---------------------------------------------------------------------------
template <int MODE>
__global__ void k_agg(const int* __restrict__ rowptr, const int2* __restrict__ edges,
                      const float* __restrict__ x, float* __restrict__ y,
                      float* __restrict__ acc) {
    const int gwid = (blockIdx.x * blockDim.x + threadIdx.x) >> 6;
    const int lane = threadIdx.x & 63;
    const int g = lane >> 4;           // group = node offset within wave
    const int l16 = lane & 15;         // dims 4*l16 .. 4*l16+3
    const int n = (gwid << 2) + g;
    if (n >= N_NODES) return;
    const int begin = rowptr[n];
    const int end = rowptr[n + 1];
    const float* xb = x + (l16 << 2);
    float4 s = make_float4(0.f, 0.f, 0.f, 0.f);
    int j = begin;
    for (; j + 3 < end; j += 4) {      // 4 independent row-gathers in flight
        int2 r0 = edges[j];
        int2 r1 = edges[j + 1];
        int2 r2 = edges[j + 2];
        int2 r3 = edges[j + 3];
        const float4 v0 = *reinterpret_cast<const float4*>(xb + (size_t)r0.x * EMB);
        const float4 v1 = *reinterpret_cast<const float4*>(xb + (size_t)r1.x * EMB);
        const float4 v2 = *reinterpret_cast<const float4*>(xb + (size_t)r2.x * EMB);
        const float4 v3 = *reinterpret_cast<const float4*>(xb + (size_t)r3.x * EMB);
        float n0 = __int_as_float(r0.y), n1 = __int_as_float(r1.y);
        float n2 = __int_as_float(r2.y), n3 = __int_as_float(r3.y);
        s.x += v0.x * n0 + v1.x * n1 + v2.x * n2 + v3.x * n3;
        s.y += v0.y * n0 + v1.y * n1 + v2.y * n2 + v3.y * n3;
        s.z += v0.z * n0 + v1.z * n1 + v2.z * n2 + v3.z * n3;
        s.w += v0.w * n0 + v1.w * n1 + v2.w * n2 + v3.w * n3;
    }
    for (; j < end; ++j) {
        int2 r0 = edges[j];
        float n0 = __int_as_float(r0.y);
        const float4 v0 = *reinterpret_cast<const float4*>(xb + (size_t)r0.x * EMB);
        s.x += v0.x * n0; s.y += v0.y * n0; s.z += v0.z * n0; s.w += v0.w * n0;
    }
    const size_t ridx = (size_t)n * EMB + (l16 << 2);
    if (MODE == 0) {
        *reinterpret_cast<float4*>(y + ridx) = s;
        float4 own = *reinterpret_cast<const float4*>(x + ridx);
        *reinterpret_cast<float4*>(acc + ridx) =
            make_float4(own.x + s.x, own.y + s.y, own.z + s.z, own.w + s.w);
    } else if (MODE == 1) {
        *reinterpret_cast<float4*>(y + ridx) = s;
        float4 a = *reinterpret_cast<const float4*>(acc + ridx);
        *reinterpret_cast<float4*>(acc + ridx) =
            make_float4(a.x + s.x, a.y + s.y, a.z + s.z, a.w + s.w);
    } else {
        float4 a = *reinterpret_cast<const float4*>(acc + ridx);
        float4 t = make_float4(a.x + s.x, a.y + s.y, a.z + s.z, a.w + s.w);
        const float sc = 0.25f / 0.9f;
        unsigned base = (unsigned)ridx;
        float4 o;
        o.x = drop_keep(base + 0u) ? t.x * sc : 0.f;
        o.y = drop_keep(base + 1u) ? t.y * sc : 0.f;
        o.z = drop_keep(base + 2u) ? t.z * sc : 0.f;
        o.w = drop_keep(base + 3u) ? t.w * sc : 0.f;
        *reinterpret_cast<float4*>(acc + ridx) = o;
    }
}

// ---------------------------------------------------------------------------
// Launch (split path; cooperative fusion measured 3.2x slower in R11)
// ---------------------------------------------------------------------------
extern "C" void kernel_launch(void* const* d_in, const int* in_sizes, int n_in,
                              void* d_out, int out_size, void* d_ws, size_t ws_size,
                              hipStream_t stream) {
    const float* emb = (const float*)d_in[0];
    const int* eidx = (const int*)d_in[1];
    const int* src = eidx;             // edge_index[0]
    const int* dst = eidx + N_EDGES;   // edge_index[1]
    float* acc = (float*)d_out;

    // workspace layout (bytes; bufA/bufB 16B-aligned)
    char* ws = (char*)d_ws;
    int*   cnt     = (int*)(ws + 0);           // 100,000 ints
    int*   cursor  = (int*)(ws + 400000);      // 100,000 ints (scan `local` alias)
    int*   bsum    = (int*)(ws + 800000);      // 98
    int*   bofs    = (int*)(ws + 800400);      // 98
    int*   rowptr  = (int*)(ws + 800800);      // 100,001
    float* dis     = (float*)(ws + 1200808);   // 100,000
    int2*  edges   = (int2*)(ws + 1600808);    // 1,200,000 int2 (8B-aligned)
    float* bufA    = (float*)(ws + 11200816);  // 6,400,000 (16B-aligned)
    float* bufB    = (float*)(ws + 36800816);  // 6,400,000; end ~62.4 MB

    const int BLK = 256;
    const int gE   = (N_EDGES + BLK - 1) / BLK;
    // 4 nodes per wave -> 25,000 waves -> 6,250 blocks
    const int gAgg = ((N_NODES + 3) / 4 * 64 + BLK - 1) / BLK;

    // CSR build
    hipMemsetAsync(cnt, 0, N_NODES * sizeof(int), stream);
    k_hist<<<gE, BLK, 0, stream>>>(dst, cnt);
    k_scan1<<<SCAN_NBLK, SCAN_CHUNK, 0, stream>>>(cnt, cursor, bsum, dis);
    k_scan2<<<1, 128, 0, stream>>>(bsum, bofs);
    k_scan3<<<SCAN_NBLK, SCAN_CHUNK, 0, stream>>>(cursor, bofs, rowptr);
    k_scatter<<<SC_GRID, SC_TPB, 0, stream>>>(src, dst, dis, cursor, edges);

    // 3 gather-only propagation layers; acc and final dropout fused
    k_agg<0><<<gAgg, BLK, 0, stream>>>(rowptr, edges, emb,  bufA, acc);
    k_agg<1><<<gAgg, BLK, 0, stream>>>(rowptr, edges, bufA, bufB, acc);
    k_agg<2><<<gAgg, BLK, 0, stream>>>(rowptr, edges, bufB, nullptr, acc);
}

// Round 13
// 324.756 us; speedup vs baseline: 3.7741x; 1.1343x over previous
//
#include <hip/hip_runtime.h>
#include <hip/hip_fp16.h>
#include <math.h>

#define N_NODES 100000
#define EMB 64
#define N_EDGES 1200000
#define N_ELEM (N_NODES * EMB)   // 6,400,000
#define SCAN_CHUNK 1024
#define SCAN_NBLK ((N_NODES + SCAN_CHUNK - 1) / SCAN_CHUNK)   // 98
#define NPART 8
#define PART_SIZE (N_NODES / NPART)    // 12,500 exact
#define SC_GRID 1024
#define SC_TPB 256

// ---------------------------------------------------------------------------
// Threefry-2x32, 20 rounds — JAX partitionable mode (verified R6-R12)
// ---------------------------------------------------------------------------
__device__ __forceinline__ unsigned rotl32(unsigned v, int r) {
    return (v << r) | (v >> (32 - r));
}

__device__ __forceinline__ void threefry2x32(unsigned k0, unsigned k1,
                                             unsigned c0, unsigned c1,
                                             unsigned& o0, unsigned& o1) {
    const unsigned ks0 = k0;
    const unsigned ks1 = k1;
    const unsigned ks2 = k0 ^ k1 ^ 0x1BD11BDAu;
    unsigned x0 = c0 + ks0;
    unsigned x1 = c1 + ks1;
#define TF_RND(r) { x0 += x1; x1 = rotl32(x1, r); x1 ^= x0; }
    TF_RND(13) TF_RND(15) TF_RND(26) TF_RND(6)
    x0 += ks1; x1 += ks2 + 1u;
    TF_RND(17) TF_RND(29) TF_RND(16) TF_RND(24)
    x0 += ks2; x1 += ks0 + 2u;
    TF_RND(13) TF_RND(15) TF_RND(26) TF_RND(6)
    x0 += ks0; x1 += ks1 + 3u;
    TF_RND(17) TF_RND(29) TF_RND(16) TF_RND(24)
    x0 += ks1; x1 += ks2 + 4u;
    TF_RND(13) TF_RND(15) TF_RND(26) TF_RND(6)
    x0 += ks2; x1 += ks0 + 5u;
#undef TF_RND
    o0 = x0;
    o1 = x1;
}

__device__ __forceinline__ bool drop_keep(unsigned i) {
    unsigned o0, o1;
    threefry2x32(0u, 42u, 0u, i, o0, o1);
    unsigned bits = o0 ^ o1;
    float u = __uint_as_float((bits >> 9) | 0x3f800000u) - 1.0f;
    return u < 0.9f;
}

// ---------------------------------------------------------------------------
// fp32 -> fp16 conversion (emb table), 8 elems/thread
// ---------------------------------------------------------------------------
__global__ void k_cvt(const float* __restrict__ in, __half* __restrict__ out) {
    int base = (blockIdx.x * blockDim.x + threadIdx.x) * 8;
    if (base >= N_ELEM) return;
    const float4 f0 = *reinterpret_cast<const float4*>(in + base);
    const float4 f1 = *reinterpret_cast<const float4*>(in + base + 4);
    __half2 h0 = __float22half2_rn(make_float2(f0.x, f0.y));
    __half2 h1 = __float22half2_rn(make_float2(f0.z, f0.w));
    __half2 h2 = __float22half2_rn(make_float2(f1.x, f1.y));
    __half2 h3 = __float22half2_rn(make_float2(f1.z, f1.w));
    uint4 u;
    u.x = *(unsigned*)&h0; u.y = *(unsigned*)&h1;
    u.z = *(unsigned*)&h2; u.w = *(unsigned*)&h3;
    *reinterpret_cast<uint4*>(out + base) = u;
}

// ---------------------------------------------------------------------------
// CSR construction (verified R9/R12)
// ---------------------------------------------------------------------------
__global__ void k_hist(const int* __restrict__ dst, int* __restrict__ cnt) {
    int e = blockIdx.x * blockDim.x + threadIdx.x;
    if (e < N_EDGES) atomicAdd(&cnt[dst[e]], 1);
}

__global__ void k_scan1(const int* __restrict__ cnt, int* __restrict__ local,
                        int* __restrict__ bsum, float* __restrict__ dis) {
    __shared__ int wsum[16];
    const int tid = threadIdx.x;
    const int lane = tid & 63;
    const int wid = tid >> 6;
    int i = blockIdx.x * SCAN_CHUNK + tid;
    int v = (i < N_NODES) ? cnt[i] : 0;
    if (i < N_NODES) dis[i] = (v > 0) ? rsqrtf((float)v) : 0.0f;
    int x = v;
#pragma unroll
    for (int off = 1; off < 64; off <<= 1) {
        int t = __shfl_up(x, off, 64);
        if (lane >= off) x += t;
    }
    if (lane == 63) wsum[wid] = x;
    __syncthreads();
    if (wid == 0 && lane < 16) {
        int w = wsum[lane];
#pragma unroll
        for (int off = 1; off < 16; off <<= 1) {
            int t = __shfl_up(w, off, 64);
            if (lane >= off) w += t;
        }
        wsum[lane] = w;
    }
    __syncthreads();
    int wexc = (wid == 0) ? 0 : wsum[wid - 1];
    if (i < N_NODES) local[i] = (x + wexc) - v;
    if (tid == 0) bsum[blockIdx.x] = wsum[15];
}

__global__ void k_scan2(const int* __restrict__ bsum, int* __restrict__ bofs) {
    __shared__ int sh[128];
    int t = threadIdx.x;
    int v = (t < SCAN_NBLK) ? bsum[t] : 0;
    sh[t] = v;
    __syncthreads();
    for (int off = 1; off < 128; off <<= 1) {
        int add = (t >= off) ? sh[t - off] : 0;
        __syncthreads();
        sh[t] += add;
        __syncthreads();
    }
    if (t < SCAN_NBLK) bofs[t] = sh[t] - v;
}

__global__ void k_scan3(int* __restrict__ cursor_local, const int* __restrict__ bofs,
                        int* __restrict__ rowptr) {
    int i = blockIdx.x * SCAN_CHUNK + threadIdx.x;
    if (i < N_NODES) {
        int r = cursor_local[i] + bofs[blockIdx.x];
        rowptr[i] = r;
        cursor_local[i] = r;
    }
    if (i == 0) rowptr[N_NODES] = N_EDGES;
}

// dst-range partitioned scatter (verified R12: write-amp fix)
__global__ void k_scatter(const int* __restrict__ src, const int* __restrict__ dst,
                          const float* __restrict__ dis, int* __restrict__ cursor,
                          int2* __restrict__ edges) {
    const int p = blockIdx.x & (NPART - 1);
    const int lo = p * PART_SIZE;
    const int hi = lo + PART_SIZE;
    const int stride = (SC_GRID / NPART) * SC_TPB;
    int e = (blockIdx.x >> 3) * SC_TPB + threadIdx.x;
    for (; e < N_EDGES; e += stride) {
        int d = dst[e];
        if (d >= lo && d < hi) {
            int s = src[e];
            int pos = atomicAdd(&cursor[d], 1);
            edges[pos] = make_int2(s, __float_as_int(dis[s] * dis[d]));
        }
    }
}

// ---------------------------------------------------------------------------
// Propagation v4: fp16 gather rows (128 B). 4 nodes/wave, one per 16-lane
// group; lane loads 8 B (4 halves) per row; x4 edge unroll. acc path fp32.
// MODE 0: y = sum (fp16); acc = own_fp32 + sum
// MODE 1: y = sum (fp16); acc += sum
// MODE 2: acc = dropout((acc + sum)/4)   [no y write]
// ---------------------------------------------------------------------------
__device__ __forceinline__ float4 h4_to_f4(uint2 u) {
    __half2 p = *(__half2*)&u.x, q = *(__half2*)&u.y;
    float2 a = __half22float2(p), b = __half22float2(q);
    return make_float4(a.x, a.y, b.x, b.y);
}

template <int MODE>
__global__ void k_agg(const int* __restrict__ rowptr, const int2* __restrict__ edges,
                      const __half* __restrict__ x, __half* __restrict__ y,
                      const float* __restrict__ own, float* __restrict__ acc) {
    const int gwid = (blockIdx.x * blockDim.x + threadIdx.x) >> 6;
    const int lane = threadIdx.x & 63;
    const int g = lane >> 4;           // group = node offset within wave
    const int l16 = lane & 15;         // dims 4*l16 .. 4*l16+3
    const int n = (gwid << 2) + g;
    if (n >= N_NODES) return;
    const int begin = rowptr[n];
    const int end = rowptr[n + 1];
    const __half* xb = x + (l16 << 2);
    float4 s = make_float4(0.f, 0.f, 0.f, 0.f);
    int j = begin;
    for (; j + 3 < end; j += 4) {      // 4 independent row-gathers in flight
        int2 r0 = edges[j];
        int2 r1 = edges[j + 1];
        int2 r2 = edges[j + 2];
        int2 r3 = edges[j + 3];
        uint2 u0 = *reinterpret_cast<const uint2*>(xb + (size_t)r0.x * EMB);
        uint2 u1 = *reinterpret_cast<const uint2*>(xb + (size_t)r1.x * EMB);
        uint2 u2 = *reinterpret_cast<const uint2*>(xb + (size_t)r2.x * EMB);
        uint2 u3 = *reinterpret_cast<const uint2*>(xb + (size_t)r3.x * EMB);
        float4 v0 = h4_to_f4(u0), v1 = h4_to_f4(u1), v2 = h4_to_f4(u2), v3 = h4_to_f4(u3);
        float n0 = __int_as_float(r0.y), n1 = __int_as_float(r1.y);
        float n2 = __int_as_float(r2.y), n3 = __int_as_float(r3.y);
        s.x += v0.x * n0 + v1.x * n1 + v2.x * n2 + v3.x * n3;
        s.y += v0.y * n0 + v1.y * n1 + v2.y * n2 + v3.y * n3;
        s.z += v0.z * n0 + v1.z * n1 + v2.z * n2 + v3.z * n3;
        s.w += v0.w * n0 + v1.w * n1 + v2.w * n2 + v3.w * n3;
    }
    for (; j < end; ++j) {
        int2 r0 = edges[j];
        float n0 = __int_as_float(r0.y);
        float4 v0 = h4_to_f4(*reinterpret_cast<const uint2*>(xb + (size_t)r0.x * EMB));
        s.x += v0.x * n0; s.y += v0.y * n0; s.z += v0.z * n0; s.w += v0.w * n0;
    }
    const size_t ridx = (size_t)n * EMB + (l16 << 2);
    if (MODE == 0 || MODE == 1) {
        __half2 h0 = __float22half2_rn(make_float2(s.x, s.y));
        __half2 h1 = __float22half2_rn(make_float2(s.z, s.w));
        uint2 u;
        u.x = *(unsigned*)&h0; u.y = *(unsigned*)&h1;
        *reinterpret_cast<uint2*>(y + ridx) = u;
        if (MODE == 0) {
            float4 o = *reinterpret_cast<const float4*>(own + ridx);
            *reinterpret_cast<float4*>(acc + ridx) =
                make_float4(o.x + s.x, o.y + s.y, o.z + s.z, o.w + s.w);
        } else {
            float4 a = *reinterpret_cast<const float4*>(acc + ridx);
            *reinterpret_cast<float4*>(acc + ridx) =
                make_float4(a.x + s.x, a.y + s.y, a.z + s.z, a.w + s.w);
        }
    } else {
        float4 a = *reinterpret_cast<const float4*>(acc + ridx);
        float4 t = make_float4(a.x + s.x, a.y + s.y, a.z + s.z, a.w + s.w);
        const float sc = 0.25f / 0.9f;
        unsigned base = (unsigned)ridx;
        float4 o;
        o.x = drop_keep(base + 0u) ? t.x * sc : 0.f;
        o.y = drop_keep(base + 1u) ? t.y * sc : 0.f;
        o.z = drop_keep(base + 2u) ? t.z * sc : 0.f;
        o.w = drop_keep(base + 3u) ? t.w * sc : 0.f;
        *reinterpret_cast<float4*>(acc + ridx) = o;
    }
}

// ---------------------------------------------------------------------------
// Launch (split path; cooperative fusion measured 3.2x slower in R11)
// ---------------------------------------------------------------------------
extern "C" void kernel_launch(void* const* d_in, const int* in_sizes, int n_in,
                              void* d_out, int out_size, void* d_ws, size_t ws_size,
                              hipStream_t stream) {
    const float* emb = (const float*)d_in[0];
    const int* eidx = (const int*)d_in[1];
    const int* src = eidx;             // edge_index[0]
    const int* dst = eidx + N_EDGES;   // edge_index[1]
    float* acc = (float*)d_out;

    // workspace layout (bytes; fp16 bufs 16B-aligned)
    char* ws = (char*)d_ws;
    int*    cnt     = (int*)(ws + 0);           // 100,000 ints
    int*    cursor  = (int*)(ws + 400000);      // 100,000 ints (scan `local` alias)
    int*    bsum    = (int*)(ws + 800000);      // 98
    int*    bofs    = (int*)(ws + 800400);      // 98
    int*    rowptr  = (int*)(ws + 800800);      // 100,001
    float*  dis     = (float*)(ws + 1200808);   // 100,000
    int2*   edges   = (int2*)(ws + 1600808);    // 1,200,000 int2 -> ends 11,200,808
    __half* embh    = (__half*)(ws + 11200816); // 6.4M halves -> ends 24,000,816
    __half* bufAh   = (__half*)(ws + 24000832); // 6.4M halves -> ends 36,800,832
    __half* bufBh   = (__half*)(ws + 36800832); // 6.4M halves -> ends 49,600,832 (~50 MB)

    const int BLK = 256;
    const int gE   = (N_EDGES + BLK - 1) / BLK;
    const int gCvt = (N_ELEM / 8 + BLK - 1) / BLK;
    // 4 nodes per wave -> 25,000 waves -> 6,250 blocks
    const int gAgg = ((N_NODES + 3) / 4 * 64 + BLK - 1) / BLK;

    // emb -> fp16 table
    k_cvt<<<gCvt, BLK, 0, stream>>>(emb, embh);

    // CSR build
    hipMemsetAsync(cnt, 0, N_NODES * sizeof(int), stream);
    k_hist<<<gE, BLK, 0, stream>>>(dst, cnt);
    k_scan1<<<SCAN_NBLK, SCAN_CHUNK, 0, stream>>>(cnt, cursor, bsum, dis);
    k_scan2<<<1, 128, 0, stream>>>(bsum, bofs);
    k_scan3<<<SCAN_NBLK, SCAN_CHUNK, 0, stream>>>(cursor, bofs, rowptr);
    k_scatter<<<SC_GRID, SC_TPB, 0, stream>>>(src, dst, dis, cursor, edges);

    // 3 gather-only propagation layers (fp16 gathers, fp32 acc)
    k_agg<0><<<gAgg, BLK, 0, stream>>>(rowptr, edges, embh,  bufAh, emb, acc);
    k_agg<1><<<gAgg, BLK, 0, stream>>>(rowptr, edges, bufAh, bufBh, nullptr, acc);
    k_agg<2><<<gAgg, BLK, 0, stream>>>(rowptr, edges, bufBh, nullptr, nullptr, acc);
}